// Round 3
// baseline (936.511 us; speedup 1.0000x reference)
//
#include <hip/hip_runtime.h>
#include <stdint.h>

#define HN 16
#define DHD 64
#define NSEQ 1024
#define JCOL 1026
#define JP 1056   // PV k-pad (mult of 32)
#define JP2 1088  // dots n-pad (mult of 64)
#define ROTD 32
#define MASKV -3.402823466e+38f

typedef unsigned short ushort_t;
typedef __attribute__((ext_vector_type(8))) short short8;
typedef __attribute__((ext_vector_type(4))) float f32x4;

__device__ inline ushort_t f2b(float f){ union{float f; unsigned int i;} v; v.f=f; unsigned x=v.i;
  return (ushort_t)((x + 0x7FFFu + ((x>>16)&1u))>>16); }

__device__ inline void gld16(const void* g, void* l){
  __builtin_amdgcn_global_load_lds((const __attribute__((address_space(1))) void*)g,
                                   (__attribute__((address_space(3))) void*)l, 16, 0, 0);
}

// ---------------- zero pads ----------------
__global__ void k_zero(uint4* p, int n4){
  int i = blockIdx.x*blockDim.x + threadIdx.x;
  if (i < n4) p[i] = make_uint4(0u,0u,0u,0u);
}

// ---------------- convert x (fp32) -> bf16 ----------------
__global__ __launch_bounds__(256) void k_x2b(const float4* __restrict__ x, ushort_t* __restrict__ xb){
  int i = blockIdx.x*blockDim.x + threadIdx.x;   // 524288 float4s
  float4 v = x[i];
  ushort_t* d = xb + (size_t)i*4;
  d[0]=f2b(v.x); d[1]=f2b(v.y); d[2]=f2b(v.z); d[3]=f2b(v.w);
}

// ---------------- transpose+convert 1024x1024 fp32 -> bf16 (4 matrices) ----------------
__global__ __launch_bounds__(256) void k_transpose(const float* w0, const float* w1,
                                                   const float* w2, const float* w3,
                                                   ushort_t* outw){
  const float* src = blockIdx.z==0?w0: blockIdx.z==1?w1: blockIdx.z==2?w2: w3;
  ushort_t* dst = outw + (size_t)blockIdx.z*1024*1024;
  __shared__ float t[64][65];
  int tid = threadIdx.x;
  int bx = blockIdx.x*64, by = blockIdx.y*64;
  #pragma unroll
  for (int p=0;p<16;p++){
    int idx = tid + p*256; int r = idx>>6, c = idx&63;
    t[r][c] = src[(size_t)(by + r)*1024 + bx + c];
  }
  __syncthreads();
  #pragma unroll
  for (int p=0;p<16;p++){
    int idx = tid + p*256; int a = idx>>6, c2 = idx&63;
    dst[(size_t)(bx + a)*1024 + by + c2] = f2b(t[c2][a]);
  }
}

// ---------------- QKV projection GEMM: XW(2048x3072) fp32 ----------------
__global__ __launch_bounds__(256) void k_qkv(const ushort_t* __restrict__ xb,
                                             const ushort_t* __restrict__ wt,
                                             float* __restrict__ xw){
  __shared__ __attribute__((aligned(16))) ushort_t As[64*32];
  __shared__ __attribute__((aligned(16))) ushort_t Bs[64*32];
  int tid = threadIdx.x;
  int m0 = blockIdx.x*64;
  int nt = blockIdx.y;                       // 0..47
  const ushort_t* wsel = wt + (size_t)(nt>>4)*1024*1024;
  int c0 = (nt&15)*64;
  int w = tid>>6, lane = tid&63, n15 = lane&15, quad = lane>>4;
  int r = tid>>2, seg = tid&3;
  f32x4 acc[4];
  #pragma unroll
  for (int t=0;t<4;t++) acc[t] = (f32x4){0.f,0.f,0.f,0.f};
  for (int k0=0;k0<1024;k0+=32){
    __syncthreads();
    gld16(xb   + (size_t)(m0 + r)*1024 + k0 + seg*8, (void*)(As + tid*8));
    gld16(wsel + (size_t)(c0 + r)*1024 + k0 + seg*8, (void*)(Bs + tid*8));
    __builtin_amdgcn_s_waitcnt(0);
    __syncthreads();
    short8 a = *(const short8*)(As + (w*16 + n15)*32 + quad*8);
    #pragma unroll
    for (int t=0;t<4;t++){
      short8 b = *(const short8*)(Bs + (t*16 + n15)*32 + quad*8);
      acc[t] = __builtin_amdgcn_mfma_f32_16x16x32_bf16(a, b, acc[t], 0,0,0);
    }
  }
  int rowbase = m0 + w*16 + quad*4;
  #pragma unroll
  for (int t=0;t<4;t++)
    #pragma unroll
    for (int rr=0;rr<4;rr++)
      xw[(size_t)(rowbase+rr)*3072 + nt*64 + t*16 + n15] = acc[t][rr];
}

// ---------------- rotary + l2norm + layout ----------------
__global__ __launch_bounds__(256) void k_postproc(const float* __restrict__ xw,
        const float* __restrict__ rpe, ushort_t* __restrict__ Qn,
        ushort_t* __restrict__ Kn, ushort_t* __restrict__ Vt){
  int row = blockIdx.x;             // b*1024+n
  int b = row >> 10, n = row & 1023;
  int tid = threadIdx.x;
  int h = tid >> 4, l16 = tid & 15;
  const float* xr = xw + (size_t)row*3072;
  float c4[4]={0,0,0,0}, s4[4]={0,0,0,0};
  #pragma unroll
  for (int jj=0; jj<4; jj++){
    int d = l16*4 + jj;
    if (d < ROTD){ float f = rpe[n*ROTD + d]; c4[jj]=__cosf(f); s4[jj]=__sinf(f); }
  }
  #pragma unroll
  for (int which=0; which<3; which++){
    const float* src = xr + which*1024 + h*64;
    float val[4];
    #pragma unroll
    for (int jj=0; jj<4; jj++){
      int d = l16*4 + jj;
      float xv = src[d];
      if (d < ROTD){
        float px = src[d<16 ? d+16 : d-16];
        val[jj] = xv*c4[jj] + (d<16 ? -px : px)*s4[jj];
      } else val[jj] = xv;
    }
    if (which < 2){
      float ss = val[0]*val[0]+val[1]*val[1]+val[2]*val[2]+val[3]*val[3];
      #pragma unroll
      for (int off=1; off<16; off<<=1) ss += __shfl_xor(ss, off, 16);
      float sc = 1.f / fmaxf(sqrtf(ss), 1e-12f);
      if (which==0){
        ushort_t* dst = Qn + ((size_t)(b*16+h)*NSEQ + n)*64 + l16*4;
        #pragma unroll
        for (int jj=0;jj<4;jj++) dst[jj] = f2b(val[jj]*sc);
      } else {
        ushort_t* dst = Kn + ((size_t)(b*16+h)*JP2 + (n+2))*64 + l16*4;
        #pragma unroll
        for (int jj=0;jj<4;jj++) dst[jj] = f2b(val[jj]*sc);
      }
    } else {
      #pragma unroll
      for (int jj=0;jj<4;jj++){
        int d = l16*4+jj;
        Vt[((size_t)(b*16+h)*64 + d)*JP + (n+2)] = f2b(val[jj]);
      }
    }
  }
}

// ---------------- memory slots ----------------
__global__ void k_mem(const float* __restrict__ mem_k, const float* __restrict__ mem_v,
                      ushort_t* __restrict__ Kn, ushort_t* __restrict__ Vt){
  int tid = threadIdx.x;
  int d = tid & 63;
  int sub = tid >> 6;   // wave id 0..3
  for (int p=0; p<8; p++){
    int pp = p*4 + sub; int h = pp >> 1, m = pp & 1;
    float kv = mem_k[(h*2+m)*64 + d];
    float ss = kv*kv;
    #pragma unroll
    for (int off=1; off<64; off<<=1) ss += __shfl_xor(ss, off);
    float sc = 1.f/fmaxf(sqrtf(ss), 1e-12f);
    ushort_t kb = f2b(kv*sc);
    ushort_t vb = f2b(mem_v[(h*2+m)*64 + d]);
    for (int b=0;b<2;b++){
      Kn[((size_t)(b*16+h)*JP2 + m)*64 + d] = kb;
      Vt[((size_t)(b*16+h)*64 + d)*JP + m] = vb;
    }
  }
}

// ---------------- dots = 10 * Qn . Kn^T -> pre (d_out, fp32) ----------------
__global__ __launch_bounds__(256) void k_dots(const ushort_t* __restrict__ Qn,
        const ushort_t* __restrict__ Kn, float* __restrict__ pre){
  __shared__ __attribute__((aligned(16))) ushort_t As[64*64];
  __shared__ __attribute__((aligned(16))) ushort_t Bs[64*64];
  int tid = threadIdx.x;
  int m0 = blockIdx.x*64;
  int n0 = blockIdx.y*64;          // within JP2
  int bh = blockIdx.z;
  const ushort_t* A  = Qn + (size_t)bh*NSEQ*64 + (size_t)m0*64;
  const ushort_t* Bb = Kn + (size_t)bh*JP2*64 + (size_t)n0*64;
  int w = tid>>6, lane = tid&63, n15 = lane&15, quad = lane>>4;
  gld16(A  + tid*8,        (void*)(As + tid*8));
  gld16(A  + 2048 + tid*8, (void*)(As + 2048 + tid*8));
  gld16(Bb + tid*8,        (void*)(Bs + tid*8));
  gld16(Bb + 2048 + tid*8, (void*)(Bs + 2048 + tid*8));
  __builtin_amdgcn_s_waitcnt(0);
  __syncthreads();
  f32x4 acc[4];
  #pragma unroll
  for (int t=0;t<4;t++) acc[t] = (f32x4){0.f,0.f,0.f,0.f};
  #pragma unroll
  for (int kq=0;kq<2;kq++){
    short8 a = *(const short8*)(As + (w*16+n15)*64 + kq*32 + quad*8);
    #pragma unroll
    for (int t=0;t<4;t++){
      short8 b = *(const short8*)(Bs + (t*16+n15)*64 + kq*32 + quad*8);
      acc[t] = __builtin_amdgcn_mfma_f32_16x16x32_bf16(a, b, acc[t], 0,0,0);
    }
  }
  int rowbase = m0 + w*16 + quad*4;
  #pragma unroll
  for (int t=0;t<4;t++){
    #pragma unroll
    for (int rr=0;rr<4;rr++){
      int col = n0 + t*16 + n15;
      if (col < JCOL)
        pre[((size_t)bh*NSEQ + rowbase+rr)*JCOL + col] = acc[t][rr]*10.f;
    }
  }
}

// ---------------- th_pre mix + mask + top64 + softmax + th_post mix ----------------
__global__ __launch_bounds__(512) void k_mixsoft(const float* __restrict__ pre,
        float* __restrict__ post, ushort_t* __restrict__ AM,
        const float* __restrict__ th_pre, const float* __restrict__ th_post){
  __shared__ float S[16*1032];
  __shared__ float TP[256];
  __shared__ float TQ[256];
  int tid = threadIdx.x;
  int blk = blockIdx.x;
  int b = blk >> 10, i = blk & 1023;
  if (tid < 256){ TP[tid] = th_pre[tid]; TQ[tid] = th_post[tid]; }
  for (int g=0; g<16; g++){
    const float* src = pre + ((size_t)(b*16+g)*NSEQ + i)*JCOL;
    for (int j=tid; j<JCOL; j+=512) S[g*1032 + j] = src[j];
  }
  __syncthreads();
  for (int j=tid; j<JCOL; j+=512){
    if (j > i + 2){
      #pragma unroll
      for (int h=0;h<16;h++) S[h*1032 + j] = MASKV;
    } else {
      float v[16];
      #pragma unroll
      for (int g=0;g<16;g++) v[g] = S[g*1032 + j];
      float o[16];
      #pragma unroll
      for (int h=0;h<16;h++){
        float a = 0.f;
        #pragma unroll
        for (int g=0;g<16;g++) a += TP[h*16+g]*v[g];
        o[h] = a;
      }
      #pragma unroll
      for (int h=0;h<16;h++) S[h*1032 + j] = o[h];
    }
  }
  __syncthreads();
  int wv = tid>>6, lane = tid&63;
  for (int rw=0; rw<2; rw++){
    int h = wv + rw*8;
    unsigned keys[17]; float vals[17];
    #pragma unroll
    for (int r=0;r<17;r++){
      int j = lane + r*64;
      float fv = (j<JCOL) ? S[h*1032+j] : 0.f;
      vals[r] = fv;
      unsigned u = __float_as_uint(fv);
      unsigned kk = (u & 0x80000000u) ? ~u : (u | 0x80000000u);
      keys[r] = (j<JCOL) ? kk : 0u;
    }
    // exact top-64 threshold: largest T with count(keys >= T) >= 64
    unsigned T = 0;
    for (int bit=31; bit>=0; bit--){
      unsigned Tt = T | (1u<<bit);
      int c = 0;
      #pragma unroll
      for (int r=0;r<17;r++) c += __popcll(__ballot(keys[r] >= Tt));
      if (c >= 64) T = Tt;
    }
    float mx = -INFINITY;
    #pragma unroll
    for (int r=0;r<17;r++){
      int j = lane + r*64;
      if (j<JCOL) mx = fmaxf(mx, vals[r]);
    }
    #pragma unroll
    for (int off=32; off>=1; off>>=1) mx = fmaxf(mx, __shfl_xor(mx, off));
    float e[17]; float s = 0.f;
    #pragma unroll
    for (int r=0;r<17;r++){
      float ev = (keys[r] >= T) ? __expf(vals[r] - mx) : 0.f;
      e[r] = ev; s += ev;
    }
    #pragma unroll
    for (int off=32; off>=1; off>>=1) s += __shfl_xor(s, off);
    float inv = 1.f / s;
    #pragma unroll
    for (int r=0;r<17;r++){
      int j = lane + r*64;
      if (j<JCOL) S[h*1032+j] = e[r]*inv;
    }
  }
  __syncthreads();
  for (int g=0; g<16; g++){
    float* dst = post + ((size_t)(b*16+g)*NSEQ + i)*JCOL;
    for (int j=tid; j<JCOL; j+=512) dst[j] = S[g*1032 + j];
  }
  for (int j=tid; j<JP; j+=512){
    if (j < JCOL){
      float v[16];
      #pragma unroll
      for (int g=0;g<16;g++) v[g] = S[g*1032 + j];
      #pragma unroll
      for (int h=0;h<16;h++){
        float a = 0.f;
        #pragma unroll
        for (int g=0;g<16;g++) a += TQ[h*16+g]*v[g];
        AM[((size_t)(b*16+h)*NSEQ + i)*JP + j] = f2b(a);
      }
    } else {
      #pragma unroll
      for (int h=0;h<16;h++) AM[((size_t)(b*16+h)*NSEQ + i)*JP + j] = 0;
    }
  }
}

// ---------------- PV: O1 = AM . Vt^T ----------------
__global__ __launch_bounds__(256) void k_pv(const ushort_t* __restrict__ AM,
        const ushort_t* __restrict__ Vt, ushort_t* __restrict__ O1){
  __shared__ __attribute__((aligned(16))) ushort_t As[64*32];
  __shared__ __attribute__((aligned(16))) ushort_t Bs[64*32];
  int tid = threadIdx.x;
  int m0 = blockIdx.x*64;
  int bh = blockIdx.y;
  const ushort_t* Ab = AM + (size_t)bh*NSEQ*JP + (size_t)m0*JP;
  const ushort_t* Bb = Vt + (size_t)bh*64*JP;
  int w=tid>>6, lane=tid&63, n15=lane&15, quad=lane>>4;
  int r=tid>>2, seg=tid&3;
  f32x4 acc[4];
  #pragma unroll
  for (int t=0;t<4;t++) acc[t] = (f32x4){0.f,0.f,0.f,0.f};
  for (int k0=0;k0<JP;k0+=32){
    __syncthreads();
    gld16(Ab + (size_t)r*JP + k0 + seg*8, (void*)(As + tid*8));
    gld16(Bb + (size_t)r*JP + k0 + seg*8, (void*)(Bs + tid*8));
    __builtin_amdgcn_s_waitcnt(0);
    __syncthreads();
    short8 a = *(const short8*)(As + (w*16+n15)*32 + quad*8);
    #pragma unroll
    for (int t=0;t<4;t++){
      short8 b = *(const short8*)(Bs + (t*16+n15)*32 + quad*8);
      acc[t] = __builtin_amdgcn_mfma_f32_16x16x32_bf16(a, b, acc[t], 0,0,0);
    }
  }
  int b_ = bh>>4, h_ = bh&15;
  int rowbase = m0 + w*16 + quad*4;
  #pragma unroll
  for (int t=0;t<4;t++)
    #pragma unroll
    for (int rr=0;rr<4;rr++)
      O1[((size_t)b_*NSEQ + rowbase+rr)*1024 + h_*64 + t*16 + n15] = f2b(acc[t][rr]);
}

// ---------------- out = O1 . WoT^T (fp32 out) ----------------
__global__ __launch_bounds__(256) void k_outproj(const ushort_t* __restrict__ o1,
        const ushort_t* __restrict__ wot, float* __restrict__ outp){
  __shared__ __attribute__((aligned(16))) ushort_t As[64*32];
  __shared__ __attribute__((aligned(16))) ushort_t Bs[64*32];
  int tid = threadIdx.x;
  int m0 = blockIdx.x*64;
  int n0 = blockIdx.y*64;
  int w = tid>>6, lane = tid&63, n15 = lane&15, quad = lane>>4;
  int r = tid>>2, seg = tid&3;
  f32x4 acc[4];
  #pragma unroll
  for (int t=0;t<4;t++) acc[t] = (f32x4){0.f,0.f,0.f,0.f};
  for (int k0=0;k0<1024;k0+=32){
    __syncthreads();
    gld16(o1  + (size_t)(m0 + r)*1024 + k0 + seg*8, (void*)(As + tid*8));
    gld16(wot + (size_t)(n0 + r)*1024 + k0 + seg*8, (void*)(Bs + tid*8));
    __builtin_amdgcn_s_waitcnt(0);
    __syncthreads();
    short8 a = *(const short8*)(As + (w*16 + n15)*32 + quad*8);
    #pragma unroll
    for (int t=0;t<4;t++){
      short8 b = *(const short8*)(Bs + (t*16 + n15)*32 + quad*8);
      acc[t] = __builtin_amdgcn_mfma_f32_16x16x32_bf16(a, b, acc[t], 0,0,0);
    }
  }
  int rowbase = m0 + w*16 + quad*4;
  #pragma unroll
  for (int t=0;t<4;t++)
    #pragma unroll
    for (int rr=0;rr<4;rr++)
      outp[(size_t)(rowbase+rr)*1024 + n0 + t*16 + n15] = acc[t][rr];
}

extern "C" void kernel_launch(void* const* d_in, const int* in_sizes, int n_in,
                              void* d_out, int out_size, void* d_ws, size_t ws_size,
                              hipStream_t stream){
  const float* x   = (const float*)d_in[0];
  const float* rpe = (const float*)d_in[1];
  const float* Wq  = (const float*)d_in[2];
  const float* Wk  = (const float*)d_in[3];
  const float* Wv  = (const float*)d_in[4];
  const float* Wo  = (const float*)d_in[5];
  const float* mk  = (const float*)d_in[6];
  const float* mv  = (const float*)d_in[7];
  const float* thp = (const float*)d_in[8];
  const float* thq = (const float*)d_in[9];
  char* ws = (char*)d_ws;
  // layout (XW aliases AM; XW dead before k_mixsoft writes AM)
  float*    XW = (float*)(ws + 0);                 // 2048*3072 fp32 = 25.2 MB
  ushort_t* AM = (ushort_t*)(ws + 0);              // 2*16*1024*1056 bf16 = 69.2 MB
  ushort_t* Qn = (ushort_t*)(ws + 69206016);       // 4.19 MB
  ushort_t* Kn = (ushort_t*)(ws + 73400320);       // 4.46 MB (rows padded to 1088)
  ushort_t* Vt = (ushort_t*)(ws + 77856768);       // 4.33 MB (cols padded to 1056)
  ushort_t* O1 = (ushort_t*)(ws + 82182144);       // 4.19 MB
  ushort_t* WT = (ushort_t*)(ws + 86376448);       // 4 x 2.10 MB transposed bf16 weights
  ushort_t* Xb = (ushort_t*)(ws + 94765056);       // 4.19 MB bf16 x
  float* out0 = (float*)d_out;
  float* pre  = out0 + 2097152;
  float* post = pre + 33619968;

  k_zero<<<2144, 256, 0, stream>>>((uint4*)Kn, 548864);            // Kn+Vt contiguous
  k_x2b<<<2048, 256, 0, stream>>>((const float4*)x, Xb);
  k_transpose<<<dim3(16,16,4), 256, 0, stream>>>(Wq, Wk, Wv, Wo, WT);
  k_qkv<<<dim3(32,48), 256, 0, stream>>>(Xb, WT, XW);
  k_postproc<<<2048, 256, 0, stream>>>(XW, rpe, Qn, Kn, Vt);
  k_mem<<<1, 256, 0, stream>>>(mk, mv, Kn, Vt);
  k_dots<<<dim3(16,17,32), 256, 0, stream>>>(Qn, Kn, pre);
  k_mixsoft<<<2048, 512, 0, stream>>>(pre, post, AM, thp, thq);
  k_pv<<<dim3(16,32), 256, 0, stream>>>(AM, Vt, O1);
  k_outproj<<<dim3(32,16), 256, 0, stream>>>(O1, WT + 3*1048576, out0);
}

// Round 4
// 615.251 us; speedup vs baseline: 1.5222x; 1.5222x over previous
//
#include <hip/hip_runtime.h>
#include <stdint.h>

#define HN 16
#define DHD 64
#define NSEQ 1024
#define JCOL 1026
#define JP 1056   // PV k-pad (mult of 32)
#define JP2 1088  // dots n-pad (mult of 64)
#define ROTD 32
#define MASKV -3.402823466e+38f

typedef unsigned short ushort_t;
typedef __attribute__((ext_vector_type(8))) short short8;
typedef __attribute__((ext_vector_type(4))) float f32x4;

__device__ inline ushort_t f2b(float f){ union{float f; unsigned int i;} v; v.f=f; unsigned x=v.i;
  return (ushort_t)((x + 0x7FFFu + ((x>>16)&1u))>>16); }

__device__ inline void gld16(const void* g, void* l){
  __builtin_amdgcn_global_load_lds((const __attribute__((address_space(1))) void*)g,
                                   (__attribute__((address_space(3))) void*)l, 16, 0, 0);
}

// ---------------- zero pads ----------------
__global__ void k_zero(uint4* p, int n4){
  int i = blockIdx.x*blockDim.x + threadIdx.x;
  if (i < n4) p[i] = make_uint4(0u,0u,0u,0u);
}

// ---------------- convert x (fp32) -> bf16 ----------------
__global__ __launch_bounds__(256) void k_x2b(const float4* __restrict__ x, ushort_t* __restrict__ xb){
  int i = blockIdx.x*blockDim.x + threadIdx.x;   // 524288 float4s
  float4 v = x[i];
  ushort_t* d = xb + (size_t)i*4;
  d[0]=f2b(v.x); d[1]=f2b(v.y); d[2]=f2b(v.z); d[3]=f2b(v.w);
}

// ---------------- transpose+convert 1024x1024 fp32 -> bf16 (4 matrices) ----------------
__global__ __launch_bounds__(256) void k_transpose(const float* w0, const float* w1,
                                                   const float* w2, const float* w3,
                                                   ushort_t* outw){
  const float* src = blockIdx.z==0?w0: blockIdx.z==1?w1: blockIdx.z==2?w2: w3;
  ushort_t* dst = outw + (size_t)blockIdx.z*1024*1024;
  __shared__ float t[64][65];
  int tid = threadIdx.x;
  int bx = blockIdx.x*64, by = blockIdx.y*64;
  #pragma unroll
  for (int p=0;p<16;p++){
    int idx = tid + p*256; int r = idx>>6, c = idx&63;
    t[r][c] = src[(size_t)(by + r)*1024 + bx + c];
  }
  __syncthreads();
  #pragma unroll
  for (int p=0;p<16;p++){
    int idx = tid + p*256; int a = idx>>6, c2 = idx&63;
    dst[(size_t)(bx + a)*1024 + by + c2] = f2b(t[c2][a]);
  }
}

// ---------------- QKV projection GEMM: XW(2048x3072) fp32 ----------------
__global__ __launch_bounds__(256) void k_qkv(const ushort_t* __restrict__ xb,
                                             const ushort_t* __restrict__ wt,
                                             float* __restrict__ xw){
  __shared__ __attribute__((aligned(16))) ushort_t As[64*32];
  __shared__ __attribute__((aligned(16))) ushort_t Bs[64*32];
  int tid = threadIdx.x;
  int m0 = blockIdx.x*64;
  int nt = blockIdx.y;                       // 0..47
  const ushort_t* wsel = wt + (size_t)(nt>>4)*1024*1024;
  int c0 = (nt&15)*64;
  int w = tid>>6, lane = tid&63, n15 = lane&15, quad = lane>>4;
  int r = tid>>2, seg = tid&3;
  f32x4 acc[4];
  #pragma unroll
  for (int t=0;t<4;t++) acc[t] = (f32x4){0.f,0.f,0.f,0.f};
  for (int k0=0;k0<1024;k0+=32){
    __syncthreads();
    gld16(xb   + (size_t)(m0 + r)*1024 + k0 + seg*8, (void*)(As + tid*8));
    gld16(wsel + (size_t)(c0 + r)*1024 + k0 + seg*8, (void*)(Bs + tid*8));
    __builtin_amdgcn_s_waitcnt(0);
    __syncthreads();
    short8 a = *(const short8*)(As + (w*16 + n15)*32 + quad*8);
    #pragma unroll
    for (int t=0;t<4;t++){
      short8 b = *(const short8*)(Bs + (t*16 + n15)*32 + quad*8);
      acc[t] = __builtin_amdgcn_mfma_f32_16x16x32_bf16(a, b, acc[t], 0,0,0);
    }
  }
  int rowbase = m0 + w*16 + quad*4;
  #pragma unroll
  for (int t=0;t<4;t++)
    #pragma unroll
    for (int rr=0;rr<4;rr++)
      xw[(size_t)(rowbase+rr)*3072 + nt*64 + t*16 + n15] = acc[t][rr];
}

// ---------------- rotary + l2norm + layout ----------------
__global__ __launch_bounds__(256) void k_postproc(const float* __restrict__ xw,
        const float* __restrict__ rpe, ushort_t* __restrict__ Qn,
        ushort_t* __restrict__ Kn, ushort_t* __restrict__ Vt){
  int row = blockIdx.x;             // b*1024+n
  int b = row >> 10, n = row & 1023;
  int tid = threadIdx.x;
  int h = tid >> 4, l16 = tid & 15;
  const float* xr = xw + (size_t)row*3072;
  float c4[4]={0,0,0,0}, s4[4]={0,0,0,0};
  #pragma unroll
  for (int jj=0; jj<4; jj++){
    int d = l16*4 + jj;
    if (d < ROTD){ float f = rpe[n*ROTD + d]; c4[jj]=__cosf(f); s4[jj]=__sinf(f); }
  }
  #pragma unroll
  for (int which=0; which<3; which++){
    const float* src = xr + which*1024 + h*64;
    float val[4];
    #pragma unroll
    for (int jj=0; jj<4; jj++){
      int d = l16*4 + jj;
      float xv = src[d];
      if (d < ROTD){
        float px = src[d<16 ? d+16 : d-16];
        val[jj] = xv*c4[jj] + (d<16 ? -px : px)*s4[jj];
      } else val[jj] = xv;
    }
    if (which < 2){
      float ss = val[0]*val[0]+val[1]*val[1]+val[2]*val[2]+val[3]*val[3];
      #pragma unroll
      for (int off=1; off<16; off<<=1) ss += __shfl_xor(ss, off, 16);
      float sc = 1.f / fmaxf(sqrtf(ss), 1e-12f);
      if (which==0){
        ushort_t* dst = Qn + ((size_t)(b*16+h)*NSEQ + n)*64 + l16*4;
        #pragma unroll
        for (int jj=0;jj<4;jj++) dst[jj] = f2b(val[jj]*sc);
      } else {
        ushort_t* dst = Kn + ((size_t)(b*16+h)*JP2 + (n+2))*64 + l16*4;
        #pragma unroll
        for (int jj=0;jj<4;jj++) dst[jj] = f2b(val[jj]*sc);
      }
    } else {
      #pragma unroll
      for (int jj=0;jj<4;jj++){
        int d = l16*4+jj;
        Vt[((size_t)(b*16+h)*64 + d)*JP + (n+2)] = f2b(val[jj]);
      }
    }
  }
}

// ---------------- memory slots ----------------
__global__ void k_mem(const float* __restrict__ mem_k, const float* __restrict__ mem_v,
                      ushort_t* __restrict__ Kn, ushort_t* __restrict__ Vt){
  int tid = threadIdx.x;
  int d = tid & 63;
  int sub = tid >> 6;   // wave id 0..3
  for (int p=0; p<8; p++){
    int pp = p*4 + sub; int h = pp >> 1, m = pp & 1;
    float kv = mem_k[(h*2+m)*64 + d];
    float ss = kv*kv;
    #pragma unroll
    for (int off=1; off<64; off<<=1) ss += __shfl_xor(ss, off);
    float sc = 1.f/fmaxf(sqrtf(ss), 1e-12f);
    ushort_t kb = f2b(kv*sc);
    ushort_t vb = f2b(mem_v[(h*2+m)*64 + d]);
    for (int b=0;b<2;b++){
      Kn[((size_t)(b*16+h)*JP2 + m)*64 + d] = kb;
      Vt[((size_t)(b*16+h)*64 + d)*JP + m] = vb;
    }
  }
}

// ---------------- dots = 10 * Qn . Kn^T -> pre (d_out, fp32) ----------------
__global__ __launch_bounds__(256) void k_dots(const ushort_t* __restrict__ Qn,
        const ushort_t* __restrict__ Kn, float* __restrict__ pre){
  __shared__ __attribute__((aligned(16))) ushort_t As[64*64];
  __shared__ __attribute__((aligned(16))) ushort_t Bs[64*64];
  int tid = threadIdx.x;
  int m0 = blockIdx.x*64;
  int n0 = blockIdx.y*64;          // within JP2
  int bh = blockIdx.z;
  const ushort_t* A  = Qn + (size_t)bh*NSEQ*64 + (size_t)m0*64;
  const ushort_t* Bb = Kn + (size_t)bh*JP2*64 + (size_t)n0*64;
  int w = tid>>6, lane = tid&63, n15 = lane&15, quad = lane>>4;
  gld16(A  + tid*8,        (void*)(As + tid*8));
  gld16(A  + 2048 + tid*8, (void*)(As + 2048 + tid*8));
  gld16(Bb + tid*8,        (void*)(Bs + tid*8));
  gld16(Bb + 2048 + tid*8, (void*)(Bs + 2048 + tid*8));
  __builtin_amdgcn_s_waitcnt(0);
  __syncthreads();
  f32x4 acc[4];
  #pragma unroll
  for (int t=0;t<4;t++) acc[t] = (f32x4){0.f,0.f,0.f,0.f};
  #pragma unroll
  for (int kq=0;kq<2;kq++){
    short8 a = *(const short8*)(As + (w*16+n15)*64 + kq*32 + quad*8);
    #pragma unroll
    for (int t=0;t<4;t++){
      short8 b = *(const short8*)(Bs + (t*16+n15)*64 + kq*32 + quad*8);
      acc[t] = __builtin_amdgcn_mfma_f32_16x16x32_bf16(a, b, acc[t], 0,0,0);
    }
  }
  int rowbase = m0 + w*16 + quad*4;
  #pragma unroll
  for (int t=0;t<4;t++){
    #pragma unroll
    for (int rr=0;rr<4;rr++){
      int col = n0 + t*16 + n15;
      if (col < JCOL)
        pre[((size_t)bh*NSEQ + rowbase+rr)*JCOL + col] = acc[t][rr]*10.f;
    }
  }
}

// ---------------- th_pre mix + mask + top64 + softmax + th_post mix ----------------
// One wave per head-row; causal-range-only work; 3 barriers.
__global__ __launch_bounds__(1024, 4) void k_mixsoft(const float* __restrict__ pre,
        float* __restrict__ post, ushort_t* __restrict__ AM,
        const float* __restrict__ th_pre, const float* __restrict__ th_post){
  __shared__ float S[16*1032];
  int tid = threadIdx.x;
  int lane = tid & 63, h = tid >> 6;       // wave h owns row h
  int blk = blockIdx.x;
  int b = blk >> 10, i = blk & 1023;
  int vend = i + 3;                        // valid cols [0, vend)
  int rmax = (vend + 63) >> 6;             // active 64-col segments (wave-uniform)

  // phase 1: wave h stages row h's valid range into LDS
  {
    const float* src = pre + ((size_t)(b*16+h)*NSEQ + i)*JCOL;
    for (int j=lane; j<vend; j+=64) S[h*1032 + j] = src[j];
  }
  __syncthreads();

  // phase 2: mix row h into registers (th_pre)
  float TPr[16];
  #pragma unroll
  for (int g=0;g<16;g++) TPr[g] = th_pre[h*16+g];
  float mixed[17];
  #pragma unroll
  for (int r=0;r<17;r++){
    mixed[r] = MASKV;
    if (r < rmax){
      int j = r*64 + lane;
      if (j < vend){
        float a = 0.f;
        #pragma unroll
        for (int g=0; g<16; g++) a += TPr[g]*S[g*1032 + j];
        mixed[r] = a;
      }
    }
  }
  __syncthreads();   // all raw reads done; S may be overwritten below

  // phase 3: exact top-64 threshold via 32-bit key bisection (valid segs only)
  unsigned keys[17];
  #pragma unroll
  for (int r=0;r<17;r++){
    unsigned u = __float_as_uint(mixed[r]);
    keys[r] = (u & 0x80000000u) ? ~u : (u | 0x80000000u);
  }
  unsigned T = 0;
  for (int bit=31; bit>=0; bit--){
    unsigned Tt = T | (1u<<bit);
    int c = 0;
    #pragma unroll
    for (int r=0;r<17;r++) if (r < rmax) c += __popcll(__ballot(keys[r] >= Tt));
    if (c >= 64) T = Tt;
  }
  float mx = -INFINITY;
  #pragma unroll
  for (int r=0;r<17;r++) if (r < rmax) mx = fmaxf(mx, mixed[r]);
  #pragma unroll
  for (int off=32; off>=1; off>>=1) mx = fmaxf(mx, __shfl_xor(mx, off));
  float e[17]; float s = 0.f;
  #pragma unroll
  for (int r=0;r<17;r++){
    e[r] = 0.f;
    if (r < rmax){
      float ev = (keys[r] >= T) ? __expf(mixed[r] - mx) : 0.f;
      e[r] = ev; s += ev;
    }
  }
  #pragma unroll
  for (int off=32; off>=1; off>>=1) s += __shfl_xor(s, off);
  float inv = 1.f / s;

  // phase 4: write post row h (valid from regs, masked tail zero) + stash into LDS
  {
    float* dst = post + ((size_t)(b*16+h)*NSEQ + i)*JCOL;
    #pragma unroll
    for (int r=0;r<17;r++) if (r < rmax){
      int j = r*64 + lane;
      if (j < vend){ float p = e[r]*inv; dst[j] = p; S[h*1032 + j] = p; }
    }
    for (int j=vend+lane; j<JCOL; j+=64) dst[j] = 0.f;
  }
  __syncthreads();

  // phase 5: th_post mix -> AM row h (bf16), masked tail zero
  float TQr[16];
  #pragma unroll
  for (int g=0;g<16;g++) TQr[g] = th_post[h*16+g];
  ushort_t* am = AM + ((size_t)(b*16+h)*NSEQ + i)*JP;
  #pragma unroll
  for (int r=0;r<17;r++) if (r < rmax){
    int j = r*64 + lane;
    if (j < vend){
      float a = 0.f;
      #pragma unroll
      for (int g=0; g<16; g++) a += TQr[g]*S[g*1032 + j];
      am[j] = f2b(a);
    }
  }
  for (int j=vend+lane; j<JP; j+=64) am[j] = 0;
}

// ---------------- PV: O1 = AM . Vt^T ----------------
__global__ __launch_bounds__(256) void k_pv(const ushort_t* __restrict__ AM,
        const ushort_t* __restrict__ Vt, ushort_t* __restrict__ O1){
  __shared__ __attribute__((aligned(16))) ushort_t As[64*32];
  __shared__ __attribute__((aligned(16))) ushort_t Bs[64*32];
  int tid = threadIdx.x;
  int m0 = blockIdx.x*64;
  int bh = blockIdx.y;
  const ushort_t* Ab = AM + (size_t)bh*NSEQ*JP + (size_t)m0*JP;
  const ushort_t* Bb = Vt + (size_t)bh*64*JP;
  int w=tid>>6, lane=tid&63, n15=lane&15, quad=lane>>4;
  int r=tid>>2, seg=tid&3;
  f32x4 acc[4];
  #pragma unroll
  for (int t=0;t<4;t++) acc[t] = (f32x4){0.f,0.f,0.f,0.f};
  for (int k0=0;k0<JP;k0+=32){
    __syncthreads();
    gld16(Ab + (size_t)r*JP + k0 + seg*8, (void*)(As + tid*8));
    gld16(Bb + (size_t)r*JP + k0 + seg*8, (void*)(Bs + tid*8));
    __builtin_amdgcn_s_waitcnt(0);
    __syncthreads();
    short8 a = *(const short8*)(As + (w*16+n15)*32 + quad*8);
    #pragma unroll
    for (int t=0;t<4;t++){
      short8 b = *(const short8*)(Bs + (t*16+n15)*32 + quad*8);
      acc[t] = __builtin_amdgcn_mfma_f32_16x16x32_bf16(a, b, acc[t], 0,0,0);
    }
  }
  int b_ = bh>>4, h_ = bh&15;
  int rowbase = m0 + w*16 + quad*4;
  #pragma unroll
  for (int t=0;t<4;t++)
    #pragma unroll
    for (int rr=0;rr<4;rr++)
      O1[((size_t)b_*NSEQ + rowbase+rr)*1024 + h_*64 + t*16 + n15] = f2b(acc[t][rr]);
}

// ---------------- out = O1 . WoT^T (fp32 out) ----------------
__global__ __launch_bounds__(256) void k_outproj(const ushort_t* __restrict__ o1,
        const ushort_t* __restrict__ wot, float* __restrict__ outp){
  __shared__ __attribute__((aligned(16))) ushort_t As[64*32];
  __shared__ __attribute__((aligned(16))) ushort_t Bs[64*32];
  int tid = threadIdx.x;
  int m0 = blockIdx.x*64;
  int n0 = blockIdx.y*64;
  int w = tid>>6, lane = tid&63, n15 = lane&15, quad = lane>>4;
  int r = tid>>2, seg = tid&3;
  f32x4 acc[4];
  #pragma unroll
  for (int t=0;t<4;t++) acc[t] = (f32x4){0.f,0.f,0.f,0.f};
  for (int k0=0;k0<1024;k0+=32){
    __syncthreads();
    gld16(o1  + (size_t)(m0 + r)*1024 + k0 + seg*8, (void*)(As + tid*8));
    gld16(wot + (size_t)(n0 + r)*1024 + k0 + seg*8, (void*)(Bs + tid*8));
    __builtin_amdgcn_s_waitcnt(0);
    __syncthreads();
    short8 a = *(const short8*)(As + (w*16 + n15)*32 + quad*8);
    #pragma unroll
    for (int t=0;t<4;t++){
      short8 b = *(const short8*)(Bs + (t*16 + n15)*32 + quad*8);
      acc[t] = __builtin_amdgcn_mfma_f32_16x16x32_bf16(a, b, acc[t], 0,0,0);
    }
  }
  int rowbase = m0 + w*16 + quad*4;
  #pragma unroll
  for (int t=0;t<4;t++)
    #pragma unroll
    for (int rr=0;rr<4;rr++)
      outp[(size_t)(rowbase+rr)*1024 + n0 + t*16 + n15] = acc[t][rr];
}

extern "C" void kernel_launch(void* const* d_in, const int* in_sizes, int n_in,
                              void* d_out, int out_size, void* d_ws, size_t ws_size,
                              hipStream_t stream){
  const float* x   = (const float*)d_in[0];
  const float* rpe = (const float*)d_in[1];
  const float* Wq  = (const float*)d_in[2];
  const float* Wk  = (const float*)d_in[3];
  const float* Wv  = (const float*)d_in[4];
  const float* Wo  = (const float*)d_in[5];
  const float* mk  = (const float*)d_in[6];
  const float* mv  = (const float*)d_in[7];
  const float* thp = (const float*)d_in[8];
  const float* thq = (const float*)d_in[9];
  char* ws = (char*)d_ws;
  // layout (XW aliases AM; XW dead before k_mixsoft writes AM)
  float*    XW = (float*)(ws + 0);                 // 2048*3072 fp32 = 25.2 MB
  ushort_t* AM = (ushort_t*)(ws + 0);              // 2*16*1024*1056 bf16 = 69.2 MB
  ushort_t* Qn = (ushort_t*)(ws + 69206016);       // 4.19 MB
  ushort_t* Kn = (ushort_t*)(ws + 73400320);       // 4.46 MB (rows padded to 1088)
  ushort_t* Vt = (ushort_t*)(ws + 77856768);       // 4.33 MB (cols padded to 1056)
  ushort_t* O1 = (ushort_t*)(ws + 82182144);       // 4.19 MB
  ushort_t* WT = (ushort_t*)(ws + 86376448);       // 4 x 2.10 MB transposed bf16 weights
  ushort_t* Xb = (ushort_t*)(ws + 94765056);       // 4.19 MB bf16 x
  float* out0 = (float*)d_out;
  float* pre  = out0 + 2097152;
  float* post = pre + 33619968;

  k_zero<<<2144, 256, 0, stream>>>((uint4*)Kn, 548864);            // Kn+Vt contiguous
  k_x2b<<<2048, 256, 0, stream>>>((const float4*)x, Xb);
  k_transpose<<<dim3(16,16,4), 256, 0, stream>>>(Wq, Wk, Wv, Wo, WT);
  k_qkv<<<dim3(32,48), 256, 0, stream>>>(Xb, WT, XW);
  k_postproc<<<2048, 256, 0, stream>>>(XW, rpe, Qn, Kn, Vt);
  k_mem<<<1, 256, 0, stream>>>(mk, mv, Kn, Vt);
  k_dots<<<dim3(16,17,32), 256, 0, stream>>>(Qn, Kn, pre);
  k_mixsoft<<<2048, 1024, 0, stream>>>(pre, post, AM, thp, thq);
  k_pv<<<dim3(16,32), 256, 0, stream>>>(AM, Vt, O1);
  k_outproj<<<dim3(32,16), 256, 0, stream>>>(O1, WT + 3*1048576, out0);
}

// Round 5
// 610.247 us; speedup vs baseline: 1.5346x; 1.0082x over previous
//
#include <hip/hip_runtime.h>
#include <stdint.h>

#define HN 16
#define DHD 64
#define NSEQ 1024
#define JCOL 1026
#define JP 1056   // PV k-pad (mult of 32)
#define JP2 1088  // dots n-pad (mult of 64)
#define ROTD 32
#define MASKV -3.402823466e+38f

typedef unsigned short ushort_t;
typedef __attribute__((ext_vector_type(8))) short short8;
typedef __attribute__((ext_vector_type(4))) float f32x4;

__device__ inline ushort_t f2b(float f){ union{float f; unsigned int i;} v; v.f=f; unsigned x=v.i;
  return (ushort_t)((x + 0x7FFFu + ((x>>16)&1u))>>16); }

__device__ inline void gld16(const void* g, void* l){
  __builtin_amdgcn_global_load_lds((const __attribute__((address_space(1))) void*)g,
                                   (__attribute__((address_space(3))) void*)l, 16, 0, 0);
}

// ---------------- zero pads ----------------
__global__ void k_zero(uint4* p, int n4){
  int i = blockIdx.x*blockDim.x + threadIdx.x;
  if (i < n4) p[i] = make_uint4(0u,0u,0u,0u);
}

// ---------------- convert x (fp32) -> bf16 ----------------
__global__ __launch_bounds__(256) void k_x2b(const float4* __restrict__ x, ushort_t* __restrict__ xb){
  int i = blockIdx.x*blockDim.x + threadIdx.x;   // 524288 float4s
  float4 v = x[i];
  ushort_t* d = xb + (size_t)i*4;
  d[0]=f2b(v.x); d[1]=f2b(v.y); d[2]=f2b(v.z); d[3]=f2b(v.w);
}

// ---------------- transpose+convert 1024x1024 fp32 -> bf16 (4 matrices) ----------------
__global__ __launch_bounds__(256) void k_transpose(const float* w0, const float* w1,
                                                   const float* w2, const float* w3,
                                                   ushort_t* outw){
  const float* src = blockIdx.z==0?w0: blockIdx.z==1?w1: blockIdx.z==2?w2: w3;
  ushort_t* dst = outw + (size_t)blockIdx.z*1024*1024;
  __shared__ float t[64][65];
  int tid = threadIdx.x;
  int bx = blockIdx.x*64, by = blockIdx.y*64;
  #pragma unroll
  for (int p=0;p<16;p++){
    int idx = tid + p*256; int r = idx>>6, c = idx&63;
    t[r][c] = src[(size_t)(by + r)*1024 + bx + c];
  }
  __syncthreads();
  #pragma unroll
  for (int p=0;p<16;p++){
    int idx = tid + p*256; int a = idx>>6, c2 = idx&63;
    dst[(size_t)(bx + a)*1024 + by + c2] = f2b(t[c2][a]);
  }
}

// ---------------- QKV projection GEMM + fused rotary/l2norm epilogue ----------------
// nt = blockIdx.y: 0..47 -> which = nt>>4 (0=q,1=k,2=v), head h = nt&15.
__global__ __launch_bounds__(256) void k_qkv(const ushort_t* __restrict__ xb,
                                             const ushort_t* __restrict__ wt,
                                             const float* __restrict__ rpe,
                                             ushort_t* __restrict__ Qn,
                                             ushort_t* __restrict__ Kn,
                                             ushort_t* __restrict__ Vt){
  __shared__ __attribute__((aligned(16))) ushort_t As[64*32];
  __shared__ __attribute__((aligned(16))) ushort_t Bs[64*32];
  int tid = threadIdx.x;
  int m0 = blockIdx.x*64;
  int nt = blockIdx.y;
  const ushort_t* wsel = wt + (size_t)(nt>>4)*1024*1024;
  int c0 = (nt&15)*64;
  int w = tid>>6, lane = tid&63, n15 = lane&15, quad = lane>>4;
  int r = tid>>2, seg = tid&3;
  f32x4 acc[4];
  #pragma unroll
  for (int t=0;t<4;t++) acc[t] = (f32x4){0.f,0.f,0.f,0.f};
  for (int k0=0;k0<1024;k0+=32){
    __syncthreads();
    gld16(xb   + (size_t)(m0 + r)*1024 + k0 + seg*8, (void*)(As + tid*8));
    gld16(wsel + (size_t)(c0 + r)*1024 + k0 + seg*8, (void*)(Bs + tid*8));
    __builtin_amdgcn_s_waitcnt(0);
    __syncthreads();
    short8 a = *(const short8*)(As + (w*16 + n15)*32 + quad*8);
    #pragma unroll
    for (int t=0;t<4;t++){
      short8 b = *(const short8*)(Bs + (t*16 + n15)*32 + quad*8);
      acc[t] = __builtin_amdgcn_mfma_f32_16x16x32_bf16(a, b, acc[t], 0,0,0);
    }
  }
  // ---- fused epilogue: rotary (+ l2norm for q/k), direct layout stores ----
  int which = nt >> 4, h = nt & 15;
  int rowbase = m0 + w*16 + quad*4;     // global row (b*1024+n)
  int b = rowbase >> 10;
  float val[4][4];                      // [t][rr]
  #pragma unroll
  for (int rr=0; rr<4; rr++){
    int n = (rowbase + rr) & 1023;
    float f0 = rpe[n*ROTD + n15];
    float f1 = rpe[n*ROTD + 16 + n15];
    float c0r = __cosf(f0), s0r = __sinf(f0);
    float c1r = __cosf(f1), s1r = __sinf(f1);
    val[0][rr] = acc[0][rr]*c0r - acc[1][rr]*s0r;   // d<16: x*cos - x[d+16]*sin
    val[1][rr] = acc[1][rr]*c1r + acc[0][rr]*s1r;   // 16<=d<32: x*cos + x[d-16]*sin
    val[2][rr] = acc[2][rr];
    val[3][rr] = acc[3][rr];
  }
  if (which < 2){
    #pragma unroll
    for (int rr=0; rr<4; rr++){
      float ss = val[0][rr]*val[0][rr] + val[1][rr]*val[1][rr]
               + val[2][rr]*val[2][rr] + val[3][rr]*val[3][rr];
      #pragma unroll
      for (int off=1; off<16; off<<=1) ss += __shfl_xor(ss, off);
      float sc = 1.f / fmaxf(sqrtf(ss), 1e-12f);
      int n = (rowbase + rr) & 1023;
      if (which == 0){
        ushort_t* dst = Qn + ((size_t)(b*16+h)*NSEQ + n)*64;
        #pragma unroll
        for (int t=0;t<4;t++) dst[t*16 + n15] = f2b(val[t][rr]*sc);
      } else {
        ushort_t* dst = Kn + ((size_t)(b*16+h)*JP2 + (n+2))*64;
        #pragma unroll
        for (int t=0;t<4;t++) dst[t*16 + n15] = f2b(val[t][rr]*sc);
      }
    }
  } else {
    #pragma unroll
    for (int rr=0; rr<4; rr++){
      int n = (rowbase + rr) & 1023;
      #pragma unroll
      for (int t=0;t<4;t++){
        int d = t*16 + n15;
        Vt[((size_t)(b*16+h)*64 + d)*JP + (n+2)] = f2b(val[t][rr]);
      }
    }
  }
}

// ---------------- memory slots ----------------
__global__ void k_mem(const float* __restrict__ mem_k, const float* __restrict__ mem_v,
                      ushort_t* __restrict__ Kn, ushort_t* __restrict__ Vt){
  int tid = threadIdx.x;
  int d = tid & 63;
  int sub = tid >> 6;   // wave id 0..3
  for (int p=0; p<8; p++){
    int pp = p*4 + sub; int h = pp >> 1, m = pp & 1;
    float kv = mem_k[(h*2+m)*64 + d];
    float ss = kv*kv;
    #pragma unroll
    for (int off=1; off<64; off<<=1) ss += __shfl_xor(ss, off);
    float sc = 1.f/fmaxf(sqrtf(ss), 1e-12f);
    ushort_t kb = f2b(kv*sc);
    ushort_t vb = f2b(mem_v[(h*2+m)*64 + d]);
    for (int b=0;b<2;b++){
      Kn[((size_t)(b*16+h)*JP2 + m)*64 + d] = kb;
      Vt[((size_t)(b*16+h)*64 + d)*JP + m] = vb;
    }
  }
}

// ---------------- dots = 10 * Qn . Kn^T -> pre (d_out, fp32) ----------------
__global__ __launch_bounds__(256) void k_dots(const ushort_t* __restrict__ Qn,
        const ushort_t* __restrict__ Kn, float* __restrict__ pre){
  __shared__ __attribute__((aligned(16))) ushort_t As[64*64];
  __shared__ __attribute__((aligned(16))) ushort_t Bs[64*64];
  int tid = threadIdx.x;
  int m0 = blockIdx.x*64;
  int n0 = blockIdx.y*64;          // within JP2
  int bh = blockIdx.z;
  const ushort_t* A  = Qn + (size_t)bh*NSEQ*64 + (size_t)m0*64;
  const ushort_t* Bb = Kn + (size_t)bh*JP2*64 + (size_t)n0*64;
  int w = tid>>6, lane = tid&63, n15 = lane&15, quad = lane>>4;
  gld16(A  + tid*8,        (void*)(As + tid*8));
  gld16(A  + 2048 + tid*8, (void*)(As + 2048 + tid*8));
  gld16(Bb + tid*8,        (void*)(Bs + tid*8));
  gld16(Bb + 2048 + tid*8, (void*)(Bs + 2048 + tid*8));
  __builtin_amdgcn_s_waitcnt(0);
  __syncthreads();
  f32x4 acc[4];
  #pragma unroll
  for (int t=0;t<4;t++) acc[t] = (f32x4){0.f,0.f,0.f,0.f};
  #pragma unroll
  for (int kq=0;kq<2;kq++){
    short8 a = *(const short8*)(As + (w*16+n15)*64 + kq*32 + quad*8);
    #pragma unroll
    for (int t=0;t<4;t++){
      short8 b = *(const short8*)(Bs + (t*16+n15)*64 + kq*32 + quad*8);
      acc[t] = __builtin_amdgcn_mfma_f32_16x16x32_bf16(a, b, acc[t], 0,0,0);
    }
  }
  int rowbase = m0 + w*16 + quad*4;
  #pragma unroll
  for (int t=0;t<4;t++){
    #pragma unroll
    for (int rr=0;rr<4;rr++){
      int col = n0 + t*16 + n15;
      if (col < JCOL)
        pre[((size_t)bh*NSEQ + rowbase+rr)*JCOL + col] = acc[t][rr]*10.f;
    }
  }
}

// ---------------- th_pre mix + mask + top64 + softmax + th_post mix ----------------
// One wave per head-row; SEGS-templated register arrays; 2-bit bisection.
template<int SEGS>
__global__ __launch_bounds__(1024) void k_mixsoft_t(const float* __restrict__ pre,
        float* __restrict__ post, ushort_t* __restrict__ AM,
        const float* __restrict__ th_pre, const float* __restrict__ th_post,
        int ibase){
  constexpr int STRIDE = SEGS*64 + 8;
  __shared__ float S[16*STRIDE];
  int tid = threadIdx.x;
  int lane = tid & 63, h = tid >> 6;       // wave h owns row h
  int blk = blockIdx.x;
  int b = blk >> 9, i = ibase + (blk & 511);
  int vend = i + 3;                        // valid cols [0, vend)
  int rmax = (vend + 63) >> 6;             // active 64-col segments (wave-uniform)

  // phase 1: wave h stages row h's valid range into LDS
  {
    const float* src = pre + ((size_t)(b*16+h)*NSEQ + i)*JCOL;
    float* dstS = S + h*STRIDE;
    for (int j=lane; j<vend; j+=64) dstS[j] = src[j];
  }
  __syncthreads();

  // phase 2: mix row h into registers (th_pre)
  float TPr[16];
  #pragma unroll
  for (int g=0;g<16;g++) TPr[g] = th_pre[h*16+g];
  float mixed[SEGS];
  #pragma unroll
  for (int r=0;r<SEGS;r++){
    mixed[r] = MASKV;
    if (r < rmax){
      int j = r*64 + lane;
      if (j < vend){
        float a = 0.f;
        #pragma unroll
        for (int g=0; g<16; g++) a += TPr[g]*S[g*STRIDE + j];
        mixed[r] = a;
      }
    }
  }
  __syncthreads();   // all raw reads done; S reused for post below

  // phase 3: exact top-64 threshold, 2 bits per iteration (16 serial steps)
  unsigned keys[SEGS];
  #pragma unroll
  for (int r=0;r<SEGS;r++){
    unsigned u = __float_as_uint(mixed[r]);
    keys[r] = (u & 0x80000000u) ? ~u : (u | 0x80000000u);
  }
  unsigned T = 0;
  for (int it=15; it>=0; --it){
    unsigned b1 = 1u << (2*it+1), b0 = 1u << (2*it);
    unsigned t3 = T|b1|b0, t2 = T|b1, t1 = T|b0;
    int c3=0, c2=0, c1=0;
    #pragma unroll
    for (int r=0;r<SEGS;r++){
      c3 += __popcll(__ballot(keys[r] >= t3));
      c2 += __popcll(__ballot(keys[r] >= t2));
      c1 += __popcll(__ballot(keys[r] >= t1));
    }
    T = (c3>=64) ? t3 : (c2>=64) ? t2 : (c1>=64) ? t1 : T;
  }
  float mx = -INFINITY;
  #pragma unroll
  for (int r=0;r<SEGS;r++) mx = fmaxf(mx, mixed[r]);
  #pragma unroll
  for (int off=32; off>=1; off>>=1) mx = fmaxf(mx, __shfl_xor(mx, off));
  float e[SEGS]; float s = 0.f;
  #pragma unroll
  for (int r=0;r<SEGS;r++){
    float ev = (keys[r] >= T) ? __expf(mixed[r] - mx) : 0.f;
    e[r] = ev; s += ev;
  }
  #pragma unroll
  for (int off=32; off>=1; off>>=1) s += __shfl_xor(s, off);
  float inv = 1.f / s;

  // phase 4: write post row h (valid from regs, masked tail zero) + stash into LDS
  {
    float* dst = post + ((size_t)(b*16+h)*NSEQ + i)*JCOL;
    #pragma unroll
    for (int r=0;r<SEGS;r++) if (r < rmax){
      int j = r*64 + lane;
      if (j < vend){ float p = e[r]*inv; dst[j] = p; S[h*STRIDE + j] = p; }
    }
    for (int j=vend+lane; j<JCOL; j+=64) dst[j] = 0.f;
  }
  __syncthreads();

  // phase 5: th_post mix -> AM row h (bf16), masked tail zero
  float TQr[16];
  #pragma unroll
  for (int g=0;g<16;g++) TQr[g] = th_post[h*16+g];
  ushort_t* am = AM + ((size_t)(b*16+h)*NSEQ + i)*JP;
  #pragma unroll
  for (int r=0;r<SEGS;r++) if (r < rmax){
    int j = r*64 + lane;
    if (j < vend){
      float a = 0.f;
      #pragma unroll
      for (int g=0; g<16; g++) a += TQr[g]*S[g*STRIDE + j];
      am[j] = f2b(a);
    }
  }
  for (int j=vend+lane; j<JP; j+=64) am[j] = 0;
}

// ---------------- PV: O1 = AM . Vt^T ----------------
__global__ __launch_bounds__(256) void k_pv(const ushort_t* __restrict__ AM,
        const ushort_t* __restrict__ Vt, ushort_t* __restrict__ O1){
  __shared__ __attribute__((aligned(16))) ushort_t As[64*32];
  __shared__ __attribute__((aligned(16))) ushort_t Bs[64*32];
  int tid = threadIdx.x;
  int m0 = blockIdx.x*64;
  int bh = blockIdx.y;
  const ushort_t* Ab = AM + (size_t)bh*NSEQ*JP + (size_t)m0*JP;
  const ushort_t* Bb = Vt + (size_t)bh*64*JP;
  int w=tid>>6, lane=tid&63, n15=lane&15, quad=lane>>4;
  int r=tid>>2, seg=tid&3;
  f32x4 acc[4];
  #pragma unroll
  for (int t=0;t<4;t++) acc[t] = (f32x4){0.f,0.f,0.f,0.f};
  for (int k0=0;k0<JP;k0+=32){
    __syncthreads();
    gld16(Ab + (size_t)r*JP + k0 + seg*8, (void*)(As + tid*8));
    gld16(Bb + (size_t)r*JP + k0 + seg*8, (void*)(Bs + tid*8));
    __builtin_amdgcn_s_waitcnt(0);
    __syncthreads();
    short8 a = *(const short8*)(As + (w*16+n15)*32 + quad*8);
    #pragma unroll
    for (int t=0;t<4;t++){
      short8 b = *(const short8*)(Bs + (t*16+n15)*32 + quad*8);
      acc[t] = __builtin_amdgcn_mfma_f32_16x16x32_bf16(a, b, acc[t], 0,0,0);
    }
  }
  int b_ = bh>>4, h_ = bh&15;
  int rowbase = m0 + w*16 + quad*4;
  #pragma unroll
  for (int t=0;t<4;t++)
    #pragma unroll
    for (int rr=0;rr<4;rr++)
      O1[((size_t)b_*NSEQ + rowbase+rr)*1024 + h_*64 + t*16 + n15] = f2b(acc[t][rr]);
}

// ---------------- out = O1 . WoT^T (fp32 out) ----------------
__global__ __launch_bounds__(256) void k_outproj(const ushort_t* __restrict__ o1,
        const ushort_t* __restrict__ wot, float* __restrict__ outp){
  __shared__ __attribute__((aligned(16))) ushort_t As[64*32];
  __shared__ __attribute__((aligned(16))) ushort_t Bs[64*32];
  int tid = threadIdx.x;
  int m0 = blockIdx.x*64;
  int n0 = blockIdx.y*64;
  int w = tid>>6, lane = tid&63, n15 = lane&15, quad = lane>>4;
  int r = tid>>2, seg = tid&3;
  f32x4 acc[4];
  #pragma unroll
  for (int t=0;t<4;t++) acc[t] = (f32x4){0.f,0.f,0.f,0.f};
  for (int k0=0;k0<1024;k0+=32){
    __syncthreads();
    gld16(o1  + (size_t)(m0 + r)*1024 + k0 + seg*8, (void*)(As + tid*8));
    gld16(wot + (size_t)(n0 + r)*1024 + k0 + seg*8, (void*)(Bs + tid*8));
    __builtin_amdgcn_s_waitcnt(0);
    __syncthreads();
    short8 a = *(const short8*)(As + (w*16 + n15)*32 + quad*8);
    #pragma unroll
    for (int t=0;t<4;t++){
      short8 b = *(const short8*)(Bs + (t*16 + n15)*32 + quad*8);
      acc[t] = __builtin_amdgcn_mfma_f32_16x16x32_bf16(a, b, acc[t], 0,0,0);
    }
  }
  int rowbase = m0 + w*16 + quad*4;
  #pragma unroll
  for (int t=0;t<4;t++)
    #pragma unroll
    for (int rr=0;rr<4;rr++)
      outp[(size_t)(rowbase+rr)*1024 + n0 + t*16 + n15] = acc[t][rr];
}

extern "C" void kernel_launch(void* const* d_in, const int* in_sizes, int n_in,
                              void* d_out, int out_size, void* d_ws, size_t ws_size,
                              hipStream_t stream){
  const float* x   = (const float*)d_in[0];
  const float* rpe = (const float*)d_in[1];
  const float* Wq  = (const float*)d_in[2];
  const float* Wk  = (const float*)d_in[3];
  const float* Wv  = (const float*)d_in[4];
  const float* Wo  = (const float*)d_in[5];
  const float* mk  = (const float*)d_in[6];
  const float* mv  = (const float*)d_in[7];
  const float* thp = (const float*)d_in[8];
  const float* thq = (const float*)d_in[9];
  char* ws = (char*)d_ws;
  ushort_t* AM = (ushort_t*)(ws + 0);              // 2*16*1024*1056 bf16 = 69.2 MB
  ushort_t* Qn = (ushort_t*)(ws + 69206016);       // 4.19 MB
  ushort_t* Kn = (ushort_t*)(ws + 73400320);       // 4.46 MB (rows padded to 1088)
  ushort_t* Vt = (ushort_t*)(ws + 77856768);       // 4.33 MB (cols padded to 1056)
  ushort_t* O1 = (ushort_t*)(ws + 82182144);       // 4.19 MB
  ushort_t* WT = (ushort_t*)(ws + 86376448);       // 4 x 2.10 MB transposed bf16 weights
  ushort_t* Xb = (ushort_t*)(ws + 94765056);       // 4.19 MB bf16 x
  float* out0 = (float*)d_out;
  float* pre  = out0 + 2097152;
  float* post = pre + 33619968;

  k_zero<<<2144, 256, 0, stream>>>((uint4*)Kn, 548864);            // Kn+Vt contiguous
  k_x2b<<<2048, 256, 0, stream>>>((const float4*)x, Xb);
  k_transpose<<<dim3(16,16,4), 256, 0, stream>>>(Wq, Wk, Wv, Wo, WT);
  k_qkv<<<dim3(32,48), 256, 0, stream>>>(Xb, WT, rpe, Qn, Kn, Vt);
  k_mem<<<1, 256, 0, stream>>>(mk, mv, Kn, Vt);
  k_dots<<<dim3(16,17,32), 256, 0, stream>>>(Qn, Kn, pre);
  k_mixsoft_t<9><<<1024, 1024, 0, stream>>>(pre, post, AM, thp, thq, 0);
  k_mixsoft_t<17><<<1024, 1024, 0, stream>>>(pre, post, AM, thp, thq, 512);
  k_pv<<<dim3(16,32), 256, 0, stream>>>(AM, Vt, O1);
  k_outproj<<<dim3(32,16), 256, 0, stream>>>(O1, WT + 3*1048576, out0);
}